// Round 8
// baseline (486.909 us; speedup 1.0000x reference)
//
#include <hip/hip_runtime.h>
#include <cstdint>
#include <cmath>

typedef unsigned short ushort_t;
typedef __bf16 bf16x8 __attribute__((ext_vector_type(8)));
typedef float f32x4 __attribute__((ext_vector_type(4)));
typedef ushort_t us4 __attribute__((ext_vector_type(4)));
typedef ushort_t us8 __attribute__((ext_vector_type(8)));

#define MFMA16(a, b, c) __builtin_amdgcn_mfma_f32_16x16x32_bf16(a, b, c, 0, 0, 0)
#define LOG2E 1.4426950408889634f

__device__ __forceinline__ ushort_t f2bf(float f) {
    union { __bf16 h; ushort_t u; } cv;
    cv.h = (__bf16)f;   // RNE
    return cv.u;
}

__device__ __forceinline__ void glds16(const ushort_t* g, ushort_t* s) {
    __builtin_amdgcn_global_load_lds(
        (const __attribute__((address_space(1))) void*)(g),
        (__attribute__((address_space(3))) void*)(s), 16, 0, 0);
}

// ---------------- fused cast f32 -> bf16 (Wq pre-scaled by log2e) + bucket LUT ----------------
__global__ void cast_all_k(const float* __restrict__ x, const float* __restrict__ wq,
                           const float* __restrict__ wk, const float* __restrict__ wv,
                           const float* __restrict__ wo, ushort_t* __restrict__ xb,
                           ushort_t* __restrict__ wb, unsigned char* __restrict__ lut) {
    int id = blockIdx.x, t = threadIdx.x;
    if (id == 8192) {
        // T5 bucket LUT: delta = j - i in [-2047, 2047]
        for (int idx = t; idx < 4095; idx += 256) {
            int rel = idx - 2047;
            int bb = (rel > 0) ? 16 : 0;
            int rp = (rel < 0) ? -rel : rel;
            int add;
            if (rp < 8) {
                add = rp;
            } else {
                // match np: correctly-rounded f32 log, then f64 divide, trunc toward zero
                float lg = (float)::log((double)rp * 0.125);
                double tt = ((double)lg) / 2.772588722239781 * 8.0;
                int large = 8 + (int)tt;
                add = (large < 15) ? large : 15;
            }
            lut[idx] = (unsigned char)(bb + add);
        }
        return;
    }
    const float* src;
    ushort_t* dst;
    int idx;
    float scale = 1.0f;
    if (id < 4096) {
        src = x; dst = xb; idx = id * 256 + t;
    } else {
        int r = (id - 4096) >> 10;
        idx = ((id - 4096) & 1023) * 256 + t;
        src = (r == 0) ? wq : (r == 1) ? wk : (r == 2) ? wv : wo;
        dst = wb + (size_t)r * 1048576;
        if (r == 0) scale = LOG2E;
    }
    float4 v = ((const float4*)src)[idx];
    us4 o;
    o.x = f2bf(v.x * scale); o.y = f2bf(v.y * scale);
    o.z = f2bf(v.z * scale); o.w = f2bf(v.w * scale);
    ((us4*)dst)[idx] = o;
}

// ---------------- GEMM: C[M,N] = A[M,K] * B[N,K]^T, bf16 in, f32 acc ----------------
// 128x128 tile, BK=64, XOR-swizzled LDS (conflict-free b128 frag reads).
// MODE 0: bf16 out row-major (+z batch); MODE 1: f32 out; MODE 2: bf16 out, V^T split addressing
template <int MODE>
__global__ __launch_bounds__(256) void gemm_bt_k(const ushort_t* __restrict__ A,
                                                 const ushort_t* __restrict__ B0,
                                                 void* __restrict__ C0,
                                                 int M, int N, int K, long sB, long sC) {
    __shared__ ushort_t As[128 * 64];
    __shared__ ushort_t Bs[128 * 64];
    const int tid = threadIdx.x;
    const int l = tid & 63, w = tid >> 6;
    const int quad = l >> 4, lc = l & 15;
    const int wm = w >> 1, wn = w & 1;
    const int m0 = blockIdx.y * 128, n0 = blockIdx.x * 128;
    const ushort_t* B = B0 + (long)blockIdx.z * sB;

    f32x4 acc[4][4] = {};
    const int rA = l >> 3;
    const int cA = ((l & 7) ^ rA) * 8;   // swizzled global chunk

    for (int k0 = 0; k0 < K; k0 += 64) {
#pragma unroll
        for (int t = 0; t < 4; ++t) {
            int row = w * 32 + t * 8;
            glds16(A + (size_t)(m0 + row + rA) * K + k0 + cA, &As[row * 64]);
            glds16(B + (size_t)(n0 + row + rA) * K + k0 + cA, &Bs[row * 64]);
        }
        __syncthreads();
#pragma unroll
        for (int ko = 0; ko < 2; ++ko) {
            const int ch = (((ko * 4 + quad) ^ (lc & 7))) * 8;
            bf16x8 af[4], bfr[4];
#pragma unroll
            for (int mt = 0; mt < 4; ++mt)
                af[mt] = *(const bf16x8*)&As[(wm * 64 + mt * 16 + lc) * 64 + ch];
#pragma unroll
            for (int nt = 0; nt < 4; ++nt)
                bfr[nt] = *(const bf16x8*)&Bs[(wn * 64 + nt * 16 + lc) * 64 + ch];
#pragma unroll
            for (int mt = 0; mt < 4; ++mt)
#pragma unroll
                for (int nt = 0; nt < 4; ++nt)
                    acc[mt][nt] = MFMA16(af[mt], bfr[nt], acc[mt][nt]);
        }
        __syncthreads();
    }
#pragma unroll
    for (int mt = 0; mt < 4; ++mt) {
#pragma unroll
        for (int nt = 0; nt < 4; ++nt) {
            int col = n0 + wn * 64 + nt * 16 + lc;
#pragma unroll
            for (int r = 0; r < 4; ++r) {
                int row = m0 + wm * 64 + mt * 16 + quad * 4 + r;
                if constexpr (MODE == 1) {
                    ((float*)C0)[(size_t)row * N + col] = acc[mt][nt][r];
                } else if constexpr (MODE == 0) {
                    (((ushort_t*)C0) + (long)blockIdx.z * sC)[(size_t)row * N + col] = f2bf(acc[mt][nt][r]);
                } else {
                    // row = feature f, col = token (b*2048+j): write VT[(b*1024+f)*2048 + j]
                    ((ushort_t*)C0)[(size_t)(col >> 11) * 2097152 + (size_t)row * 2048 + (col & 2047)] =
                        f2bf(acc[mt][nt][r]);
                }
            }
        }
    }
}

// ---------------- flash attention, S^T = K*Q^T, 1 barrier/kt, K dbuf, V ping-pong, 3 blk/CU ----------------
// 1-D grid 512: bh = id&31 (XCD-local K/V reuse), qt = id>>5. 4 waves, wave w owns q [w*32, w*32+32)
__global__ __launch_bounds__(256, 3) void attn_k(const ushort_t* __restrict__ Qg,
                                                 const ushort_t* __restrict__ Kg,
                                                 const ushort_t* __restrict__ VTg,
                                                 ushort_t* __restrict__ Ctx,
                                                 const unsigned char* __restrict__ lut,
                                                 const float* __restrict__ table,
                                                 float* __restrict__ bias_out) {
    __shared__ ushort_t Kbuf[2][128 * 64];   // K tiles [j][d] swizzled, double-buffered
    __shared__ ushort_t Pws[4 * 32 * 40];    // per-wave packed P [q][j-chunk]
    __shared__ float diag[2][256];           // raw bias diagonal, double-buffered

    const int tid = threadIdx.x, l = tid & 63, w = tid >> 6;
    const int quad = l >> 4, lc = l & 15;
    const int id = blockIdx.x;
    const int bh = id & 31, b = bh >> 4, h = bh & 15;
    const int q0 = (id >> 5) * 128;
    const size_t tokbase = (size_t)b * 2048;

    const int rK = l >> 3;
    const int cK = ((l & 7) ^ rK) * 8;

    // ---- prologue: Q -> Kbuf[1], K(kt0) -> Kbuf[0], diag[0] ----
#pragma unroll
    for (int t = 0; t < 4; ++t) {
        int row0 = w * 32 + t * 8;
        glds16(Qg + (tokbase + q0 + row0 + rK) * 1024 + h * 64 + cK, &Kbuf[1][row0 * 64]);
        glds16(Kg + (tokbase + row0 + rK) * 1024 + h * 64 + cK, &Kbuf[0][row0 * 64]);
    }
    if (tid < 255) diag[0][tid] = table[(int)lut[tid + 1920 - q0] * 16 + h];
    __syncthreads();

    // Q fragments (B-operand): lane holds Q[w*32+nt*16+lc][ko*32+quad*8+i]
    bf16x8 qf[2][2];
#pragma unroll
    for (int nt = 0; nt < 2; ++nt)
#pragma unroll
        for (int ko = 0; ko < 2; ++ko) {
            int row = w * 32 + nt * 16 + lc;
            int ch = ((ko * 4 + quad) ^ (lc & 7)) * 8;
            qf[nt][ko] = *(const bf16x8*)&Kbuf[1][row * 64 + ch];
        }
    __syncthreads();   // Kbuf[1] free for kt=0's prefetch of K(kt=1)

    float mstate[2] = {-1e30f, -1e30f};
    float lstate[2] = {0.f, 0.f};
    f32x4 acco[4][2] = {};
    ushort_t* Pw = &Pws[w * 1280];         // 32 q-rows x 40 u16
    const int cb0 = quad * 4 - (w * 32 + lc) + 127;
    const int cxor = lc & 3;               // P chunk swizzle
    const ushort_t* VTbase = VTg + (size_t)(b * 1024 + h * 64) * 2048;

    const int bjf = (tid & 15) * 4 + b * 64;   // bias patch j offset within 128-tile
    const int big = tid >> 4;

    for (int kt = 0; kt < 16; ++kt) {
        const int j0 = kt * 128;
        const int cur = kt & 1, nxt = cur ^ 1;
        const ushort_t* Kc = Kbuf[cur];
        const float* dc = diag[cur];

        // ---- fused position_bias patch NT stores FIRST (max drain window before barrier) ----
        {
            float* outp = bias_out + ((size_t)h * 2048 + q0) * 2048 + j0;
#pragma unroll
            for (int rr = 0; rr < 8; ++rr) {
                int il = big + 16 * rr;
                int d0 = bjf - il + 127;
                f32x4 v;
                v[0] = dc[d0]; v[1] = dc[d0 + 1]; v[2] = dc[d0 + 2]; v[3] = dc[d0 + 3];
                __builtin_nontemporal_store(v, (f32x4*)(outp + (size_t)il * 2048 + bjf));
            }
        }

        // ---- prefetch next K tile + next bias diagonal (drains behind this kt's compute) ----
        if (kt < 15) {
            const int jn = j0 + 128;
#pragma unroll
            for (int t = 0; t < 4; ++t) {
                int row0 = w * 32 + t * 8;
                glds16(Kg + (tokbase + jn + row0 + rK) * 1024 + h * 64 + cK, &Kbuf[nxt][row0 * 64]);
            }
            if (tid < 255) diag[nxt][tid] = table[(int)lut[jn - q0 + tid + 1920] * 16 + h];
        }

        // ---- prefetch V chunk kk=0 (direct global; hidden under QK+softmax) ----
        bf16x8 vfp[2][4];
#pragma unroll
        for (int dt = 0; dt < 4; ++dt)
            vfp[0][dt] = *(const bf16x8*)(VTbase + (size_t)(dt * 16 + lc) * 2048 + j0 + quad * 8);

        // ---- S^T = K Q^T : D[j][q], A = K rows (LDS), B = Q rows (Q pre-scaled by log2e) ----
        f32x4 accs[8][2] = {};
#pragma unroll
        for (int ko = 0; ko < 2; ++ko) {
            const int ch = ((ko * 4 + quad) ^ (lc & 7)) * 8;
#pragma unroll
            for (int mt = 0; mt < 8; ++mt) {
                bf16x8 kf = *(const bf16x8*)&Kc[(mt * 16 + lc) * 64 + ch];
                accs[mt][0] = MFMA16(kf, qf[0][ko], accs[mt][0]);
                accs[mt][1] = MFMA16(kf, qf[1][ko], accs[mt][1]);
            }
        }

        // ---- + bias via fma(raw, log2e) with rolling reuse (d = mt for nt=0, mt-1 for nt=1) ----
        float dprev[4], dcur[4];
#pragma unroll
        for (int r = 0; r < 4; ++r) dprev[r] = dc[cb0 - 16 + r];
#pragma unroll
        for (int mt = 0; mt < 8; ++mt) {
#pragma unroll
            for (int r = 0; r < 4; ++r) dcur[r] = dc[cb0 + mt * 16 + r];
#pragma unroll
            for (int r = 0; r < 4; ++r) {
                accs[mt][0][r] = fmaf(dcur[r], LOG2E, accs[mt][0][r]);
                accs[mt][1][r] = fmaf(dprev[r], LOG2E, accs[mt][1][r]);
            }
#pragma unroll
            for (int r = 0; r < 4; ++r) dprev[r] = dcur[r];
        }

        // ---- online softmax in exp2 domain: q-row = nt*16+lc over 4 quad-lanes ----
#pragma unroll
        for (int nt = 0; nt < 2; ++nt) {
            float mx = accs[0][nt][0];
#pragma unroll
            for (int mt = 0; mt < 8; ++mt)
#pragma unroll
                for (int r = 0; r < 4; ++r) mx = fmaxf(mx, accs[mt][nt][r]);
            mx = fmaxf(mx, __shfl_xor(mx, 16, 64));
            mx = fmaxf(mx, __shfl_xor(mx, 32, 64));
            float mo = mstate[nt], mn = fmaxf(mo, mx);
            float alpha = __builtin_amdgcn_exp2f(mo - mn);
            mstate[nt] = mn;
            float rs = 0.f;
#pragma unroll
            for (int mt = 0; mt < 8; ++mt)
#pragma unroll
                for (int r = 0; r < 4; ++r) {
                    float p = __builtin_amdgcn_exp2f(accs[mt][nt][r] - mn);
                    accs[mt][nt][r] = p;
                    rs += p;
                }
            rs += __shfl_xor(rs, 16, 64);
            rs += __shfl_xor(rs, 32, 64);
            lstate[nt] = lstate[nt] * alpha + rs;
#pragma unroll
            for (int dt = 0; dt < 4; ++dt) acco[dt][nt] *= alpha;
        }

        // ---- O^T += V^T P^T; V ping-pong direct loads, P wave-private LDS roundtrip ----
#pragma unroll
        for (int kk = 0; kk < 4; ++kk) {
            if (kk < 3) {
#pragma unroll
                for (int dt = 0; dt < 4; ++dt)
                    vfp[(kk + 1) & 1][dt] =
                        *(const bf16x8*)(VTbase + (size_t)(dt * 16 + lc) * 2048 +
                                         j0 + (kk + 1) * 32 + quad * 8);
            }
#pragma unroll
            for (int half = 0; half < 2; ++half) {
                int mt = kk * 2 + half;
                int c = half * 2 + (quad >> 1);
                int coff = ((c ^ cxor) * 8 + (quad & 1) * 4);
#pragma unroll
                for (int nt = 0; nt < 2; ++nt) {
                    us4 o;
#pragma unroll
                    for (int r = 0; r < 4; ++r) o[r] = f2bf(accs[mt][nt][r]);
                    *(us4*)&Pw[(nt * 16 + lc) * 40 + coff] = o;
                }
            }
            bf16x8 pf[2];
#pragma unroll
            for (int nt = 0; nt < 2; ++nt)
                pf[nt] = *(const bf16x8*)&Pw[(nt * 16 + lc) * 40 + (quad ^ cxor) * 8];
#pragma unroll
            for (int dt = 0; dt < 4; ++dt)
#pragma unroll
                for (int nt = 0; nt < 2; ++nt)
                    acco[dt][nt] = MFMA16(vfp[kk & 1][dt], pf[nt], acco[dt][nt]);
        }
        if (kt < 15) __syncthreads();   // single barrier per kt: swaps buffers + drains prefetch
    }

    // ---- epilogue: O^T lane holds (d = dt*16+quad*4+r, q = w*32+nt*16+lc) ----
#pragma unroll
    for (int nt = 0; nt < 2; ++nt) {
        float inv = 1.0f / lstate[nt];
        size_t row = tokbase + q0 + w * 32 + nt * 16 + lc;
#pragma unroll
        for (int dt = 0; dt < 4; ++dt) {
            us4 o;
#pragma unroll
            for (int r = 0; r < 4; ++r) o[r] = f2bf(acco[dt][nt][r] * inv);
            *(us4*)&Ctx[row * 1024 + h * 64 + dt * 16 + quad * 4] = o;
        }
    }
}

extern "C" void kernel_launch(void* const* d_in, const int* in_sizes, int n_in,
                              void* d_out, int out_size, void* d_ws, size_t ws_size,
                              hipStream_t stream) {
    const float* hidden = (const float*)d_in[0];
    const float* Wq = (const float*)d_in[1];
    const float* Wk = (const float*)d_in[2];
    const float* Wv = (const float*)d_in[3];
    const float* Wo = (const float*)d_in[4];
    const float* table = (const float*)d_in[5];

    char* ws = (char*)d_ws;
    ushort_t* Xb  = (ushort_t*)(ws);                    // [4096][1024] bf16
    ushort_t* Wb  = (ushort_t*)(ws + 8388608);          // Wq(*log2e),Wk,Wv,Wo each [1024][1024]
    ushort_t* Qg  = (ushort_t*)(ws + 16777216);         // [4096][1024]
    ushort_t* Kgp = (ushort_t*)(ws + 25165824);         // [4096][1024]
    ushort_t* VTg = (ushort_t*)(ws + 33554432);         // [(b*1024+f)][2048]
    ushort_t* Ctx = (ushort_t*)(ws + 41943040);         // [4096][1024]
    unsigned char* lutp = (unsigned char*)(ws + 50331648);

    float* out0 = (float*)d_out;
    float* out1 = out0 + 4194304;

    cast_all_k<<<8193, 256, 0, stream>>>(hidden, Wq, Wk, Wv, Wo, Xb, Wb, lutp);

    // Q, K projections: C[token][feat] bf16
    gemm_bt_k<0><<<dim3(8, 32, 2), 256, 0, stream>>>(Xb, Wb, (void*)Qg,
                                                     4096, 1024, 1024, 1048576, 4194304);
    // V^T: C[f][token] -> VT[(b*1024+f)][j]
    gemm_bt_k<2><<<dim3(32, 8, 1), 256, 0, stream>>>(Wb + 2097152, Xb, (void*)VTg,
                                                     1024, 4096, 1024, 0, 0);
    attn_k<<<dim3(512), 256, 0, stream>>>(Qg, Kgp, VTg, Ctx, lutp, table, out1);
    gemm_bt_k<1><<<dim3(8, 32, 1), 256, 0, stream>>>(Ctx, Wb + 3145728, (void*)out0,
                                                     4096, 1024, 1024, 0, 0);
}

// Round 9
// 465.532 us; speedup vs baseline: 1.0459x; 1.0459x over previous
//
#include <hip/hip_runtime.h>
#include <cstdint>
#include <cmath>

typedef unsigned short ushort_t;
typedef __bf16 bf16x8 __attribute__((ext_vector_type(8)));
typedef float f32x4 __attribute__((ext_vector_type(4)));
typedef ushort_t us4 __attribute__((ext_vector_type(4)));
typedef ushort_t us8 __attribute__((ext_vector_type(8)));

#define MFMA16(a, b, c) __builtin_amdgcn_mfma_f32_16x16x32_bf16(a, b, c, 0, 0, 0)
#define LOG2E 1.4426950408889634f

__device__ __forceinline__ ushort_t f2bf(float f) {
    union { __bf16 h; ushort_t u; } cv;
    cv.h = (__bf16)f;   // RNE
    return cv.u;
}

__device__ __forceinline__ void glds16(const ushort_t* g, ushort_t* s) {
    __builtin_amdgcn_global_load_lds(
        (const __attribute__((address_space(1))) void*)(g),
        (__attribute__((address_space(3))) void*)(s), 16, 0, 0);
}

// ---------------- fused cast f32 -> bf16 (Wq pre-scaled by log2e) + bucket LUT ----------------
__global__ void cast_all_k(const float* __restrict__ x, const float* __restrict__ wq,
                           const float* __restrict__ wk, const float* __restrict__ wv,
                           const float* __restrict__ wo, ushort_t* __restrict__ xb,
                           ushort_t* __restrict__ wb, unsigned char* __restrict__ lut) {
    int id = blockIdx.x, t = threadIdx.x;
    if (id == 8192) {
        // T5 bucket LUT: delta = j - i in [-2047, 2047]
        for (int idx = t; idx < 4095; idx += 256) {
            int rel = idx - 2047;
            int bb = (rel > 0) ? 16 : 0;
            int rp = (rel < 0) ? -rel : rel;
            int add;
            if (rp < 8) {
                add = rp;
            } else {
                // match np: correctly-rounded f32 log, then f64 divide, trunc toward zero
                float lg = (float)::log((double)rp * 0.125);
                double tt = ((double)lg) / 2.772588722239781 * 8.0;
                int large = 8 + (int)tt;
                add = (large < 15) ? large : 15;
            }
            lut[idx] = (unsigned char)(bb + add);
        }
        return;
    }
    const float* src;
    ushort_t* dst;
    int idx;
    float scale = 1.0f;
    if (id < 4096) {
        src = x; dst = xb; idx = id * 256 + t;
    } else {
        int r = (id - 4096) >> 10;
        idx = ((id - 4096) & 1023) * 256 + t;
        src = (r == 0) ? wq : (r == 1) ? wk : (r == 2) ? wv : wo;
        dst = wb + (size_t)r * 1048576;
        if (r == 0) scale = LOG2E;
    }
    float4 v = ((const float4*)src)[idx];
    us4 o;
    o.x = f2bf(v.x * scale); o.y = f2bf(v.y * scale);
    o.z = f2bf(v.z * scale); o.w = f2bf(v.w * scale);
    ((us4*)dst)[idx] = o;
}

// ---------------- GEMM: C[M,N] = A[M,K] * B[N,K]^T, bf16 in, f32 acc ----------------
// 128x128 tile, BK=64, XOR-swizzled LDS (conflict-free b128 frag reads).
// MODE 0: bf16 out row-major (+z batch); MODE 1: f32 out; MODE 2: bf16 out, V^T split addressing
template <int MODE>
__global__ __launch_bounds__(256) void gemm_bt_k(const ushort_t* __restrict__ A,
                                                 const ushort_t* __restrict__ B0,
                                                 void* __restrict__ C0,
                                                 int M, int N, int K, long sB, long sC) {
    __shared__ ushort_t As[128 * 64];
    __shared__ ushort_t Bs[128 * 64];
    const int tid = threadIdx.x;
    const int l = tid & 63, w = tid >> 6;
    const int quad = l >> 4, lc = l & 15;
    const int wm = w >> 1, wn = w & 1;
    const int m0 = blockIdx.y * 128, n0 = blockIdx.x * 128;
    const ushort_t* B = B0 + (long)blockIdx.z * sB;

    f32x4 acc[4][4] = {};
    const int rA = l >> 3;
    const int cA = ((l & 7) ^ rA) * 8;   // swizzled global chunk

    for (int k0 = 0; k0 < K; k0 += 64) {
#pragma unroll
        for (int t = 0; t < 4; ++t) {
            int row = w * 32 + t * 8;
            glds16(A + (size_t)(m0 + row + rA) * K + k0 + cA, &As[row * 64]);
            glds16(B + (size_t)(n0 + row + rA) * K + k0 + cA, &Bs[row * 64]);
        }
        __syncthreads();
#pragma unroll
        for (int ko = 0; ko < 2; ++ko) {
            const int ch = (((ko * 4 + quad) ^ (lc & 7))) * 8;
            bf16x8 af[4], bfr[4];
#pragma unroll
            for (int mt = 0; mt < 4; ++mt)
                af[mt] = *(const bf16x8*)&As[(wm * 64 + mt * 16 + lc) * 64 + ch];
#pragma unroll
            for (int nt = 0; nt < 4; ++nt)
                bfr[nt] = *(const bf16x8*)&Bs[(wn * 64 + nt * 16 + lc) * 64 + ch];
#pragma unroll
            for (int mt = 0; mt < 4; ++mt)
#pragma unroll
                for (int nt = 0; nt < 4; ++nt)
                    acc[mt][nt] = MFMA16(af[mt], bfr[nt], acc[mt][nt]);
        }
        __syncthreads();
    }
#pragma unroll
    for (int mt = 0; mt < 4; ++mt) {
#pragma unroll
        for (int nt = 0; nt < 4; ++nt) {
            int col = n0 + wn * 64 + nt * 16 + lc;
#pragma unroll
            for (int r = 0; r < 4; ++r) {
                int row = m0 + wm * 64 + mt * 16 + quad * 4 + r;
                if constexpr (MODE == 1) {
                    ((float*)C0)[(size_t)row * N + col] = acc[mt][nt][r];
                } else if constexpr (MODE == 0) {
                    (((ushort_t*)C0) + (long)blockIdx.z * sC)[(size_t)row * N + col] = f2bf(acc[mt][nt][r]);
                } else {
                    // row = feature f, col = token (b*2048+j): write VT[(b*1024+f)*2048 + j]
                    ((ushort_t*)C0)[(size_t)(col >> 11) * 2097152 + (size_t)row * 2048 + (col & 2047)] =
                        f2bf(acc[mt][nt][r]);
                }
            }
        }
    }
}

// ---------------- flash attention, S^T = K*Q^T, 1 barrier/kt, K dbuf, V direct ----------------
// Bias matrix written in a barrier-free epilogue from a full-diagonal LDS stage.
// 1-D grid 512: bh = id&31 (XCD-local K/V reuse), qt = id>>5. 4 waves, wave w owns q [w*32, w*32+32)
__global__ __launch_bounds__(256, 2) void attn_k(const ushort_t* __restrict__ Qg,
                                                 const ushort_t* __restrict__ Kg,
                                                 const ushort_t* __restrict__ VTg,
                                                 ushort_t* __restrict__ Ctx,
                                                 const unsigned char* __restrict__ lut,
                                                 const float* __restrict__ table,
                                                 float* __restrict__ bias_out) {
    __shared__ ushort_t Kbuf[2][128 * 64];   // K tiles [j][d] swizzled, double-buffered
    __shared__ ushort_t Pws[4 * 32 * 40];    // per-wave packed P [q][j-chunk]
    __shared__ float diagfull[2175];         // full raw bias diagonal for this (q0) block

    const int tid = threadIdx.x, l = tid & 63, w = tid >> 6;
    const int quad = l >> 4, lc = l & 15;
    const int id = blockIdx.x;
    const int bh = id & 31, b = bh >> 4, h = bh & 15;
    const int q0 = (id >> 5) * 128;
    const size_t tokbase = (size_t)b * 2048;

    const int rK = l >> 3;
    const int cK = ((l & 7) ^ rK) * 8;

    // ---- prologue: Q -> Kbuf[1], K(kt0) -> Kbuf[0], full diag ----
#pragma unroll
    for (int t = 0; t < 4; ++t) {
        int row0 = w * 32 + t * 8;
        glds16(Qg + (tokbase + q0 + row0 + rK) * 1024 + h * 64 + cK, &Kbuf[1][row0 * 64]);
        glds16(Kg + (tokbase + row0 + rK) * 1024 + h * 64 + cK, &Kbuf[0][row0 * 64]);
    }
    // diagfull[d] = bias(delta_idx = 1920 - q0 + d), d in [0, 2175)
    for (int i = tid; i < 2175; i += 256)
        diagfull[i] = table[(int)lut[i + 1920 - q0] * 16 + h];
    __syncthreads();

    // Q fragments (B-operand): lane holds Q[w*32+nt*16+lc][ko*32+quad*8+i]
    bf16x8 qf[2][2];
#pragma unroll
    for (int nt = 0; nt < 2; ++nt)
#pragma unroll
        for (int ko = 0; ko < 2; ++ko) {
            int row = w * 32 + nt * 16 + lc;
            int ch = ((ko * 4 + quad) ^ (lc & 7)) * 8;
            qf[nt][ko] = *(const bf16x8*)&Kbuf[1][row * 64 + ch];
        }
    __syncthreads();   // Kbuf[1] free for kt=0's prefetch of K(kt=1)

    float mstate[2] = {-1e30f, -1e30f};
    float lstate[2] = {0.f, 0.f};
    f32x4 acco[4][2] = {};
    ushort_t* Pw = &Pws[w * 1280];         // 32 q-rows x 40 u16
    const int cb0 = quad * 4 - (w * 32 + lc) + 127;
    const int cxor = lc & 3;               // P chunk swizzle
    const ushort_t* VTbase = VTg + (size_t)(b * 1024 + h * 64) * 2048;

    for (int kt = 0; kt < 16; ++kt) {
        const int j0 = kt * 128;
        const int cur = kt & 1, nxt = cur ^ 1;
        const ushort_t* Kc = Kbuf[cur];
        const float* dc = &diagfull[j0];

        // ---- prefetch next K tile (drains behind this kt's compute) ----
        if (kt < 15) {
            const int jn = j0 + 128;
#pragma unroll
            for (int t = 0; t < 4; ++t) {
                int row0 = w * 32 + t * 8;
                glds16(Kg + (tokbase + jn + row0 + rK) * 1024 + h * 64 + cK, &Kbuf[nxt][row0 * 64]);
            }
        }

        // ---- V fragments direct from global (A-operand rows d, k-index j) ----
        bf16x8 vf[4][4];
#pragma unroll
        for (int kk = 0; kk < 4; ++kk)
#pragma unroll
            for (int dt = 0; dt < 4; ++dt)
                vf[kk][dt] = *(const bf16x8*)(VTbase + (size_t)(dt * 16 + lc) * 2048 +
                                              j0 + kk * 32 + quad * 8);

        // ---- S^T = K Q^T : D[j][q], A = K rows (LDS), B = Q rows (Q pre-scaled by log2e) ----
        f32x4 accs[8][2] = {};
#pragma unroll
        for (int ko = 0; ko < 2; ++ko) {
            const int ch = ((ko * 4 + quad) ^ (lc & 7)) * 8;
#pragma unroll
            for (int mt = 0; mt < 8; ++mt) {
                bf16x8 kf = *(const bf16x8*)&Kc[(mt * 16 + lc) * 64 + ch];
                accs[mt][0] = MFMA16(kf, qf[0][ko], accs[mt][0]);
                accs[mt][1] = MFMA16(kf, qf[1][ko], accs[mt][1]);
            }
        }

        // ---- + bias via fma(raw, log2e) with rolling reuse (d = mt for nt=0, mt-1 for nt=1) ----
        float dprev[4], dcur[4];
#pragma unroll
        for (int r = 0; r < 4; ++r) dprev[r] = dc[cb0 - 16 + r];
#pragma unroll
        for (int mt = 0; mt < 8; ++mt) {
#pragma unroll
            for (int r = 0; r < 4; ++r) dcur[r] = dc[cb0 + mt * 16 + r];
#pragma unroll
            for (int r = 0; r < 4; ++r) {
                accs[mt][0][r] = fmaf(dcur[r], LOG2E, accs[mt][0][r]);
                accs[mt][1][r] = fmaf(dprev[r], LOG2E, accs[mt][1][r]);
            }
#pragma unroll
            for (int r = 0; r < 4; ++r) dprev[r] = dcur[r];
        }

        // ---- online softmax in exp2 domain: q-row = nt*16+lc over 4 quad-lanes ----
#pragma unroll
        for (int nt = 0; nt < 2; ++nt) {
            float mx = accs[0][nt][0];
#pragma unroll
            for (int mt = 0; mt < 8; ++mt)
#pragma unroll
                for (int r = 0; r < 4; ++r) mx = fmaxf(mx, accs[mt][nt][r]);
            mx = fmaxf(mx, __shfl_xor(mx, 16, 64));
            mx = fmaxf(mx, __shfl_xor(mx, 32, 64));
            float mo = mstate[nt], mn = fmaxf(mo, mx);
            float alpha = __builtin_amdgcn_exp2f(mo - mn);
            mstate[nt] = mn;
            float rs = 0.f;
#pragma unroll
            for (int mt = 0; mt < 8; ++mt)
#pragma unroll
                for (int r = 0; r < 4; ++r) {
                    float p = __builtin_amdgcn_exp2f(accs[mt][nt][r] - mn);
                    accs[mt][nt][r] = p;
                    rs += p;
                }
            rs += __shfl_xor(rs, 16, 64);
            rs += __shfl_xor(rs, 32, 64);
            lstate[nt] = lstate[nt] * alpha + rs;
#pragma unroll
            for (int dt = 0; dt < 4; ++dt) acco[dt][nt] *= alpha;
        }

        // ---- O^T += V^T P^T; P wave-private LDS roundtrip (b64 writes, b128 reads) ----
#pragma unroll
        for (int kk = 0; kk < 4; ++kk) {
#pragma unroll
            for (int half = 0; half < 2; ++half) {
                int mt = kk * 2 + half;
                int c = half * 2 + (quad >> 1);
                int coff = ((c ^ cxor) * 8 + (quad & 1) * 4);
#pragma unroll
                for (int nt = 0; nt < 2; ++nt) {
                    us4 o;
#pragma unroll
                    for (int r = 0; r < 4; ++r) o[r] = f2bf(accs[mt][nt][r]);
                    *(us4*)&Pw[(nt * 16 + lc) * 40 + coff] = o;
                }
            }
            bf16x8 pf[2];
#pragma unroll
            for (int nt = 0; nt < 2; ++nt)
                pf[nt] = *(const bf16x8*)&Pw[(nt * 16 + lc) * 40 + (quad ^ cxor) * 8];
#pragma unroll
            for (int dt = 0; dt < 4; ++dt)
#pragma unroll
                for (int nt = 0; nt < 2; ++nt)
                    acco[dt][nt] = MFMA16(vf[kk][dt], pf[nt], acco[dt][nt]);
        }
        if (kt < 15) __syncthreads();   // single barrier per kt: swaps K buffers
    }

    // ---- epilogue 1: Ctx store. lane holds (d = dt*16+quad*4+r, q = w*32+nt*16+lc) ----
#pragma unroll
    for (int nt = 0; nt < 2; ++nt) {
        float inv = 1.0f / lstate[nt];
        size_t row = tokbase + q0 + w * 32 + nt * 16 + lc;
#pragma unroll
        for (int dt = 0; dt < 4; ++dt) {
            us4 o;
#pragma unroll
            for (int r = 0; r < 4; ++r) o[r] = f2bf(acco[dt][nt][r] * inv);
            *(us4*)&Ctx[row * 1024 + h * 64 + dt * 16 + quad * 4] = o;
        }
    }

    // ---- epilogue 2: bias matrix patches, barrier-free NT streaming from diagfull ----
    {
        const int bjf = (tid & 15) * 4 + b * 64;   // j offset within 128-tile (b splits halves)
        const int big = tid >> 4;                  // 0..15
        float* outh = bias_out + ((size_t)h * 2048 + q0) * 2048;
        for (int kt = 0; kt < 16; ++kt) {
            const int j0 = kt * 128;
            const float* dc = &diagfull[j0];
            float* outp = outh + j0;
#pragma unroll
            for (int rr = 0; rr < 8; ++rr) {
                int il = big + 16 * rr;
                int d0 = bjf - il + 127;
                f32x4 v;
                v[0] = dc[d0]; v[1] = dc[d0 + 1]; v[2] = dc[d0 + 2]; v[3] = dc[d0 + 3];
                __builtin_nontemporal_store(v, (f32x4*)(outp + (size_t)il * 2048 + bjf));
            }
        }
    }
}

extern "C" void kernel_launch(void* const* d_in, const int* in_sizes, int n_in,
                              void* d_out, int out_size, void* d_ws, size_t ws_size,
                              hipStream_t stream) {
    const float* hidden = (const float*)d_in[0];
    const float* Wq = (const float*)d_in[1];
    const float* Wk = (const float*)d_in[2];
    const float* Wv = (const float*)d_in[3];
    const float* Wo = (const float*)d_in[4];
    const float* table = (const float*)d_in[5];

    char* ws = (char*)d_ws;
    ushort_t* Xb  = (ushort_t*)(ws);                    // [4096][1024] bf16
    ushort_t* Wb  = (ushort_t*)(ws + 8388608);          // Wq(*log2e),Wk,Wv,Wo each [1024][1024]
    ushort_t* Qg  = (ushort_t*)(ws + 16777216);         // [4096][1024]
    ushort_t* Kgp = (ushort_t*)(ws + 25165824);         // [4096][1024]
    ushort_t* VTg = (ushort_t*)(ws + 33554432);         // [(b*1024+f)][2048]
    ushort_t* Ctx = (ushort_t*)(ws + 41943040);         // [4096][1024]
    unsigned char* lutp = (unsigned char*)(ws + 50331648);

    float* out0 = (float*)d_out;
    float* out1 = out0 + 4194304;

    cast_all_k<<<8193, 256, 0, stream>>>(hidden, Wq, Wk, Wv, Wo, Xb, Wb, lutp);

    // Q, K projections: C[token][feat] bf16
    gemm_bt_k<0><<<dim3(8, 32, 2), 256, 0, stream>>>(Xb, Wb, (void*)Qg,
                                                     4096, 1024, 1024, 1048576, 4194304);
    // V^T: C[f][token] -> VT[(b*1024+f)][j]
    gemm_bt_k<2><<<dim3(32, 8, 1), 256, 0, stream>>>(Wb + 2097152, Xb, (void*)VTg,
                                                     1024, 4096, 1024, 0, 0);
    attn_k<<<dim3(512), 256, 0, stream>>>(Qg, Kgp, VTg, Ctx, lutp, table, out1);
    gemm_bt_k<1><<<dim3(8, 32, 1), 256, 0, stream>>>(Ctx, Wb + 3145728, (void*)out0,
                                                     4096, 1024, 1024, 0, 0);
}

// Round 10
// 443.153 us; speedup vs baseline: 1.0987x; 1.0505x over previous
//
#include <hip/hip_runtime.h>
#include <cstdint>
#include <cmath>

typedef unsigned short ushort_t;
typedef __bf16 bf16x8 __attribute__((ext_vector_type(8)));
typedef float f32x4 __attribute__((ext_vector_type(4)));
typedef ushort_t us4 __attribute__((ext_vector_type(4)));
typedef ushort_t us8 __attribute__((ext_vector_type(8)));

#define MFMA16(a, b, c) __builtin_amdgcn_mfma_f32_16x16x32_bf16(a, b, c, 0, 0, 0)
#define LOG2E 1.4426950408889634f

__device__ __forceinline__ ushort_t f2bf(float f) {
    union { __bf16 h; ushort_t u; } cv;
    cv.h = (__bf16)f;   // RNE
    return cv.u;
}

__device__ __forceinline__ void glds16(const ushort_t* g, ushort_t* s) {
    __builtin_amdgcn_global_load_lds(
        (const __attribute__((address_space(1))) void*)(g),
        (__attribute__((address_space(3))) void*)(s), 16, 0, 0);
}

// ---------------- fused cast f32 -> bf16 (Wq pre-scaled by log2e) + bucket LUT ----------------
__global__ void cast_all_k(const float* __restrict__ x, const float* __restrict__ wq,
                           const float* __restrict__ wk, const float* __restrict__ wv,
                           const float* __restrict__ wo, ushort_t* __restrict__ xb,
                           ushort_t* __restrict__ wb, unsigned char* __restrict__ lut) {
    int id = blockIdx.x, t = threadIdx.x;
    if (id == 8192) {
        // T5 bucket LUT: delta = j - i in [-2047, 2047]
        for (int idx = t; idx < 4095; idx += 256) {
            int rel = idx - 2047;
            int bb = (rel > 0) ? 16 : 0;
            int rp = (rel < 0) ? -rel : rel;
            int add;
            if (rp < 8) {
                add = rp;
            } else {
                // match np: correctly-rounded f32 log, then f64 divide, trunc toward zero
                float lg = (float)::log((double)rp * 0.125);
                double tt = ((double)lg) / 2.772588722239781 * 8.0;
                int large = 8 + (int)tt;
                add = (large < 15) ? large : 15;
            }
            lut[idx] = (unsigned char)(bb + add);
        }
        return;
    }
    const float* src;
    ushort_t* dst;
    int idx;
    float scale = 1.0f;
    if (id < 4096) {
        src = x; dst = xb; idx = id * 256 + t;
    } else {
        int r = (id - 4096) >> 10;
        idx = ((id - 4096) & 1023) * 256 + t;
        src = (r == 0) ? wq : (r == 1) ? wk : (r == 2) ? wv : wo;
        dst = wb + (size_t)r * 1048576;
        if (r == 0) scale = LOG2E;
    }
    float4 v = ((const float4*)src)[idx];
    us4 o;
    o.x = f2bf(v.x * scale); o.y = f2bf(v.y * scale);
    o.z = f2bf(v.z * scale); o.w = f2bf(v.w * scale);
    ((us4*)dst)[idx] = o;
}

// ---------------- GEMM: C[M,N] = A[M,K] * B[N,K]^T, bf16 in, f32 acc ----------------
// 128x128 tile, BK=64, XOR-swizzled LDS (conflict-free b128 frag reads).
// MODE 0: bf16 out row-major (+z batch); MODE 1: f32 out; MODE 2: bf16 out, V^T split addressing
template <int MODE>
__global__ __launch_bounds__(256) void gemm_bt_k(const ushort_t* __restrict__ A,
                                                 const ushort_t* __restrict__ B0,
                                                 void* __restrict__ C0,
                                                 int M, int N, int K, long sB, long sC) {
    __shared__ ushort_t As[128 * 64];
    __shared__ ushort_t Bs[128 * 64];
    const int tid = threadIdx.x;
    const int l = tid & 63, w = tid >> 6;
    const int quad = l >> 4, lc = l & 15;
    const int wm = w >> 1, wn = w & 1;
    const int m0 = blockIdx.y * 128, n0 = blockIdx.x * 128;
    const ushort_t* B = B0 + (long)blockIdx.z * sB;

    f32x4 acc[4][4] = {};
    const int rA = l >> 3;
    const int cA = ((l & 7) ^ rA) * 8;   // swizzled global chunk

    for (int k0 = 0; k0 < K; k0 += 64) {
#pragma unroll
        for (int t = 0; t < 4; ++t) {
            int row = w * 32 + t * 8;
            glds16(A + (size_t)(m0 + row + rA) * K + k0 + cA, &As[row * 64]);
            glds16(B + (size_t)(n0 + row + rA) * K + k0 + cA, &Bs[row * 64]);
        }
        __syncthreads();
#pragma unroll
        for (int ko = 0; ko < 2; ++ko) {
            const int ch = (((ko * 4 + quad) ^ (lc & 7))) * 8;
            bf16x8 af[4], bfr[4];
#pragma unroll
            for (int mt = 0; mt < 4; ++mt)
                af[mt] = *(const bf16x8*)&As[(wm * 64 + mt * 16 + lc) * 64 + ch];
#pragma unroll
            for (int nt = 0; nt < 4; ++nt)
                bfr[nt] = *(const bf16x8*)&Bs[(wn * 64 + nt * 16 + lc) * 64 + ch];
#pragma unroll
            for (int mt = 0; mt < 4; ++mt)
#pragma unroll
                for (int nt = 0; nt < 4; ++nt)
                    acc[mt][nt] = MFMA16(af[mt], bfr[nt], acc[mt][nt]);
        }
        __syncthreads();
    }
#pragma unroll
    for (int mt = 0; mt < 4; ++mt) {
#pragma unroll
        for (int nt = 0; nt < 4; ++nt) {
            int col = n0 + wn * 64 + nt * 16 + lc;
#pragma unroll
            for (int r = 0; r < 4; ++r) {
                int row = m0 + wm * 64 + mt * 16 + quad * 4 + r;
                if constexpr (MODE == 1) {
                    ((float*)C0)[(size_t)row * N + col] = acc[mt][nt][r];
                } else if constexpr (MODE == 0) {
                    (((ushort_t*)C0) + (long)blockIdx.z * sC)[(size_t)row * N + col] = f2bf(acc[mt][nt][r]);
                } else {
                    // row = feature f, col = token (b*2048+j): write VT[(b*1024+f)*2048 + j]
                    ((ushort_t*)C0)[(size_t)(col >> 11) * 2097152 + (size_t)row * 2048 + (col & 2047)] =
                        f2bf(acc[mt][nt][r]);
                }
            }
        }
    }
}

// ---------------- flash attention, S^T = K*Q^T, 1 barrier/kt, K dbuf, V direct ----------------
// Bias patch stores are PLAIN (L2 write-back) so the pre-barrier vmcnt(0) acks at L2,
// not at HBM — the 256 MB streams out via background writeback. [R9->R10 single change]
// 1-D grid 512: bh = id&31 (XCD-local K/V reuse), qt = id>>5. 4 waves, wave w owns q [w*32, w*32+32)
__global__ __launch_bounds__(256, 2) void attn_k(const ushort_t* __restrict__ Qg,
                                                 const ushort_t* __restrict__ Kg,
                                                 const ushort_t* __restrict__ VTg,
                                                 ushort_t* __restrict__ Ctx,
                                                 const unsigned char* __restrict__ lut,
                                                 const float* __restrict__ table,
                                                 float* __restrict__ bias_out) {
    __shared__ ushort_t Kbuf[2][128 * 64];   // K tiles [j][d] swizzled, double-buffered
    __shared__ ushort_t Pws[4 * 32 * 40];    // per-wave packed P [q][j-chunk]
    __shared__ float diag[2][256];           // raw bias diagonal, double-buffered

    const int tid = threadIdx.x, l = tid & 63, w = tid >> 6;
    const int quad = l >> 4, lc = l & 15;
    const int id = blockIdx.x;
    const int bh = id & 31, b = bh >> 4, h = bh & 15;
    const int q0 = (id >> 5) * 128;
    const size_t tokbase = (size_t)b * 2048;

    const int rK = l >> 3;
    const int cK = ((l & 7) ^ rK) * 8;

    // ---- prologue: Q -> Kbuf[1], K(kt0) -> Kbuf[0], diag[0] ----
#pragma unroll
    for (int t = 0; t < 4; ++t) {
        int row0 = w * 32 + t * 8;
        glds16(Qg + (tokbase + q0 + row0 + rK) * 1024 + h * 64 + cK, &Kbuf[1][row0 * 64]);
        glds16(Kg + (tokbase + row0 + rK) * 1024 + h * 64 + cK, &Kbuf[0][row0 * 64]);
    }
    if (tid < 255) diag[0][tid] = table[(int)lut[tid + 1920 - q0] * 16 + h];
    __syncthreads();

    // Q fragments (B-operand): lane holds Q[w*32+nt*16+lc][ko*32+quad*8+i]
    bf16x8 qf[2][2];
#pragma unroll
    for (int nt = 0; nt < 2; ++nt)
#pragma unroll
        for (int ko = 0; ko < 2; ++ko) {
            int row = w * 32 + nt * 16 + lc;
            int ch = ((ko * 4 + quad) ^ (lc & 7)) * 8;
            qf[nt][ko] = *(const bf16x8*)&Kbuf[1][row * 64 + ch];
        }
    __syncthreads();   // Kbuf[1] free for kt=0's prefetch of K(kt=1)

    float mstate[2] = {-1e30f, -1e30f};
    float lstate[2] = {0.f, 0.f};
    f32x4 acco[4][2] = {};
    ushort_t* Pw = &Pws[w * 1280];         // 32 q-rows x 40 u16
    const int cb0 = quad * 4 - (w * 32 + lc) + 127;
    const int cxor = lc & 3;               // P chunk swizzle
    const ushort_t* VTbase = VTg + (size_t)(b * 1024 + h * 64) * 2048;

    const int bjf = (tid & 15) * 4 + b * 64;   // bias patch j offset within 128-tile
    const int big = tid >> 4;

    for (int kt = 0; kt < 16; ++kt) {
        const int j0 = kt * 128;
        const int cur = kt & 1, nxt = cur ^ 1;
        const ushort_t* Kc = Kbuf[cur];
        const float* dc = diag[cur];

        // ---- prefetch next K tile + next bias diagonal (drains behind this kt's compute) ----
        if (kt < 15) {
            const int jn = j0 + 128;
#pragma unroll
            for (int t = 0; t < 4; ++t) {
                int row0 = w * 32 + t * 8;
                glds16(Kg + (tokbase + jn + row0 + rK) * 1024 + h * 64 + cK, &Kbuf[nxt][row0 * 64]);
            }
            if (tid < 255) diag[nxt][tid] = table[(int)lut[jn - q0 + tid + 1920] * 16 + h];
        }

        // ---- V fragments direct from global (A-operand rows d, k-index j) ----
        bf16x8 vf[4][4];
#pragma unroll
        for (int kk = 0; kk < 4; ++kk)
#pragma unroll
            for (int dt = 0; dt < 4; ++dt)
                vf[kk][dt] = *(const bf16x8*)(VTbase + (size_t)(dt * 16 + lc) * 2048 +
                                              j0 + kk * 32 + quad * 8);

        // ---- fused position_bias patch store (plain f32x4: acks at L2, not HBM) ----
        {
            float* outp = bias_out + ((size_t)h * 2048 + q0) * 2048 + j0;
#pragma unroll
            for (int rr = 0; rr < 8; ++rr) {
                int il = big + 16 * rr;
                int d0 = bjf - il + 127;
                f32x4 v;
                v[0] = dc[d0]; v[1] = dc[d0 + 1]; v[2] = dc[d0 + 2]; v[3] = dc[d0 + 3];
                *(f32x4*)(outp + (size_t)il * 2048 + bjf) = v;
            }
        }

        // ---- S^T = K Q^T : D[j][q], A = K rows (LDS), B = Q rows (Q pre-scaled by log2e) ----
        f32x4 accs[8][2] = {};
#pragma unroll
        for (int ko = 0; ko < 2; ++ko) {
            const int ch = ((ko * 4 + quad) ^ (lc & 7)) * 8;
#pragma unroll
            for (int mt = 0; mt < 8; ++mt) {
                bf16x8 kf = *(const bf16x8*)&Kc[(mt * 16 + lc) * 64 + ch];
                accs[mt][0] = MFMA16(kf, qf[0][ko], accs[mt][0]);
                accs[mt][1] = MFMA16(kf, qf[1][ko], accs[mt][1]);
            }
        }

        // ---- + bias via fma(raw, log2e) with rolling reuse (d = mt for nt=0, mt-1 for nt=1) ----
        float dprev[4], dcur[4];
#pragma unroll
        for (int r = 0; r < 4; ++r) dprev[r] = dc[cb0 - 16 + r];
#pragma unroll
        for (int mt = 0; mt < 8; ++mt) {
#pragma unroll
            for (int r = 0; r < 4; ++r) dcur[r] = dc[cb0 + mt * 16 + r];
#pragma unroll
            for (int r = 0; r < 4; ++r) {
                accs[mt][0][r] = fmaf(dcur[r], LOG2E, accs[mt][0][r]);
                accs[mt][1][r] = fmaf(dprev[r], LOG2E, accs[mt][1][r]);
            }
#pragma unroll
            for (int r = 0; r < 4; ++r) dprev[r] = dcur[r];
        }

        // ---- online softmax in exp2 domain: q-row = nt*16+lc over 4 quad-lanes ----
#pragma unroll
        for (int nt = 0; nt < 2; ++nt) {
            float mx = accs[0][nt][0];
#pragma unroll
            for (int mt = 0; mt < 8; ++mt)
#pragma unroll
                for (int r = 0; r < 4; ++r) mx = fmaxf(mx, accs[mt][nt][r]);
            mx = fmaxf(mx, __shfl_xor(mx, 16, 64));
            mx = fmaxf(mx, __shfl_xor(mx, 32, 64));
            float mo = mstate[nt], mn = fmaxf(mo, mx);
            float alpha = __builtin_amdgcn_exp2f(mo - mn);
            mstate[nt] = mn;
            float rs = 0.f;
#pragma unroll
            for (int mt = 0; mt < 8; ++mt)
#pragma unroll
                for (int r = 0; r < 4; ++r) {
                    float p = __builtin_amdgcn_exp2f(accs[mt][nt][r] - mn);
                    accs[mt][nt][r] = p;
                    rs += p;
                }
            rs += __shfl_xor(rs, 16, 64);
            rs += __shfl_xor(rs, 32, 64);
            lstate[nt] = lstate[nt] * alpha + rs;
#pragma unroll
            for (int dt = 0; dt < 4; ++dt) acco[dt][nt] *= alpha;
        }

        // ---- O^T += V^T P^T; P wave-private LDS roundtrip (b64 writes, b128 reads) ----
#pragma unroll
        for (int kk = 0; kk < 4; ++kk) {
#pragma unroll
            for (int half = 0; half < 2; ++half) {
                int mt = kk * 2 + half;
                int c = half * 2 + (quad >> 1);
                int coff = ((c ^ cxor) * 8 + (quad & 1) * 4);
#pragma unroll
                for (int nt = 0; nt < 2; ++nt) {
                    us4 o;
#pragma unroll
                    for (int r = 0; r < 4; ++r) o[r] = f2bf(accs[mt][nt][r]);
                    *(us4*)&Pw[(nt * 16 + lc) * 40 + coff] = o;
                }
            }
            bf16x8 pf[2];
#pragma unroll
            for (int nt = 0; nt < 2; ++nt)
                pf[nt] = *(const bf16x8*)&Pw[(nt * 16 + lc) * 40 + (quad ^ cxor) * 8];
#pragma unroll
            for (int dt = 0; dt < 4; ++dt)
#pragma unroll
                for (int nt = 0; nt < 2; ++nt)
                    acco[dt][nt] = MFMA16(vf[kk][dt], pf[nt], acco[dt][nt]);
        }
        if (kt < 15) __syncthreads();   // single barrier per kt: swaps buffers + drains prefetch
    }

    // ---- epilogue: O^T lane holds (d = dt*16+quad*4+r, q = w*32+nt*16+lc) ----
#pragma unroll
    for (int nt = 0; nt < 2; ++nt) {
        float inv = 1.0f / lstate[nt];
        size_t row = tokbase + q0 + w * 32 + nt * 16 + lc;
#pragma unroll
        for (int dt = 0; dt < 4; ++dt) {
            us4 o;
#pragma unroll
            for (int r = 0; r < 4; ++r) o[r] = f2bf(acco[dt][nt][r] * inv);
            *(us4*)&Ctx[row * 1024 + h * 64 + dt * 16 + quad * 4] = o;
        }
    }
}

extern "C" void kernel_launch(void* const* d_in, const int* in_sizes, int n_in,
                              void* d_out, int out_size, void* d_ws, size_t ws_size,
                              hipStream_t stream) {
    const float* hidden = (const float*)d_in[0];
    const float* Wq = (const float*)d_in[1];
    const float* Wk = (const float*)d_in[2];
    const float* Wv = (const float*)d_in[3];
    const float* Wo = (const float*)d_in[4];
    const float* table = (const float*)d_in[5];

    char* ws = (char*)d_ws;
    ushort_t* Xb  = (ushort_t*)(ws);                    // [4096][1024] bf16
    ushort_t* Wb  = (ushort_t*)(ws + 8388608);          // Wq(*log2e),Wk,Wv,Wo each [1024][1024]
    ushort_t* Qg  = (ushort_t*)(ws + 16777216);         // [4096][1024]
    ushort_t* Kgp = (ushort_t*)(ws + 25165824);         // [4096][1024]
    ushort_t* VTg = (ushort_t*)(ws + 33554432);         // [(b*1024+f)][2048]
    ushort_t* Ctx = (ushort_t*)(ws + 41943040);         // [4096][1024]
    unsigned char* lutp = (unsigned char*)(ws + 50331648);

    float* out0 = (float*)d_out;
    float* out1 = out0 + 4194304;

    cast_all_k<<<8193, 256, 0, stream>>>(hidden, Wq, Wk, Wv, Wo, Xb, Wb, lutp);

    // Q, K projections: C[token][feat] bf16
    gemm_bt_k<0><<<dim3(8, 32, 2), 256, 0, stream>>>(Xb, Wb, (void*)Qg,
                                                     4096, 1024, 1024, 1048576, 4194304);
    // V^T: C[f][token] -> VT[(b*1024+f)][j]
    gemm_bt_k<2><<<dim3(32, 8, 1), 256, 0, stream>>>(Wb + 2097152, Xb, (void*)VTg,
                                                     1024, 4096, 1024, 0, 0);
    attn_k<<<dim3(512), 256, 0, stream>>>(Qg, Kgp, VTg, Ctx, lutp, table, out1);
    gemm_bt_k<1><<<dim3(8, 32, 1), 256, 0, stream>>>(Ctx, Wb + 3145728, (void*)out0,
                                                     4096, 1024, 1024, 0, 0);
}

// Round 11
// 428.362 us; speedup vs baseline: 1.1367x; 1.0345x over previous
//
#include <hip/hip_runtime.h>
#include <cstdint>
#include <cmath>

typedef unsigned short ushort_t;
typedef __bf16 bf16x8 __attribute__((ext_vector_type(8)));
typedef float f32x4 __attribute__((ext_vector_type(4)));
typedef ushort_t us4 __attribute__((ext_vector_type(4)));
typedef ushort_t us8 __attribute__((ext_vector_type(8)));

#define MFMA16(a, b, c) __builtin_amdgcn_mfma_f32_16x16x32_bf16(a, b, c, 0, 0, 0)
#define LOG2E 1.4426950408889634f

__device__ __forceinline__ ushort_t f2bf(float f) {
    union { __bf16 h; ushort_t u; } cv;
    cv.h = (__bf16)f;   // RNE
    return cv.u;
}

__device__ __forceinline__ void glds16(const ushort_t* g, ushort_t* s) {
    __builtin_amdgcn_global_load_lds(
        (const __attribute__((address_space(1))) void*)(g),
        (__attribute__((address_space(3))) void*)(s), 16, 0, 0);
}

// ---------------- fused cast f32 -> bf16 (Wq pre-scaled by log2e) + bucket LUT ----------------
__global__ void cast_all_k(const float* __restrict__ x, const float* __restrict__ wq,
                           const float* __restrict__ wk, const float* __restrict__ wv,
                           const float* __restrict__ wo, ushort_t* __restrict__ xb,
                           ushort_t* __restrict__ wb, unsigned char* __restrict__ lut) {
    int id = blockIdx.x, t = threadIdx.x;
    if (id == 8192) {
        // T5 bucket LUT: delta = j - i in [-2047, 2047]
        for (int idx = t; idx < 4095; idx += 256) {
            int rel = idx - 2047;
            int bb = (rel > 0) ? 16 : 0;
            int rp = (rel < 0) ? -rel : rel;
            int add;
            if (rp < 8) {
                add = rp;
            } else {
                // match np: correctly-rounded f32 log, then f64 divide, trunc toward zero
                float lg = (float)::log((double)rp * 0.125);
                double tt = ((double)lg) / 2.772588722239781 * 8.0;
                int large = 8 + (int)tt;
                add = (large < 15) ? large : 15;
            }
            lut[idx] = (unsigned char)(bb + add);
        }
        return;
    }
    const float* src;
    ushort_t* dst;
    int idx;
    float scale = 1.0f;
    if (id < 4096) {
        src = x; dst = xb; idx = id * 256 + t;
    } else {
        int r = (id - 4096) >> 10;
        idx = ((id - 4096) & 1023) * 256 + t;
        src = (r == 0) ? wq : (r == 1) ? wk : (r == 2) ? wv : wo;
        dst = wb + (size_t)r * 1048576;
        if (r == 0) scale = LOG2E;
    }
    float4 v = ((const float4*)src)[idx];
    us4 o;
    o.x = f2bf(v.x * scale); o.y = f2bf(v.y * scale);
    o.z = f2bf(v.z * scale); o.w = f2bf(v.w * scale);
    ((us4*)dst)[idx] = o;
}

// ---------------- GEMM: C[M,N] = A[M,K] * B[N,K]^T, bf16 in, f32 acc ----------------
// 128x128 tile, BK=64, XOR-swizzled LDS (conflict-free b128 frag reads).
// MODE 0: bf16 out row-major (+z batch); MODE 1: f32 out; MODE 2: bf16 out, V^T split addressing
template <int MODE>
__global__ __launch_bounds__(256) void gemm_bt_k(const ushort_t* __restrict__ A,
                                                 const ushort_t* __restrict__ B0,
                                                 void* __restrict__ C0,
                                                 int M, int N, int K, long sB, long sC) {
    __shared__ ushort_t As[128 * 64];
    __shared__ ushort_t Bs[128 * 64];
    const int tid = threadIdx.x;
    const int l = tid & 63, w = tid >> 6;
    const int quad = l >> 4, lc = l & 15;
    const int wm = w >> 1, wn = w & 1;
    const int m0 = blockIdx.y * 128, n0 = blockIdx.x * 128;
    const ushort_t* B = B0 + (long)blockIdx.z * sB;

    f32x4 acc[4][4] = {};
    const int rA = l >> 3;
    const int cA = ((l & 7) ^ rA) * 8;   // swizzled global chunk

    for (int k0 = 0; k0 < K; k0 += 64) {
#pragma unroll
        for (int t = 0; t < 4; ++t) {
            int row = w * 32 + t * 8;
            glds16(A + (size_t)(m0 + row + rA) * K + k0 + cA, &As[row * 64]);
            glds16(B + (size_t)(n0 + row + rA) * K + k0 + cA, &Bs[row * 64]);
        }
        __syncthreads();
#pragma unroll
        for (int ko = 0; ko < 2; ++ko) {
            const int ch = (((ko * 4 + quad) ^ (lc & 7))) * 8;
            bf16x8 af[4], bfr[4];
#pragma unroll
            for (int mt = 0; mt < 4; ++mt)
                af[mt] = *(const bf16x8*)&As[(wm * 64 + mt * 16 + lc) * 64 + ch];
#pragma unroll
            for (int nt = 0; nt < 4; ++nt)
                bfr[nt] = *(const bf16x8*)&Bs[(wn * 64 + nt * 16 + lc) * 64 + ch];
#pragma unroll
            for (int mt = 0; mt < 4; ++mt)
#pragma unroll
                for (int nt = 0; nt < 4; ++nt)
                    acc[mt][nt] = MFMA16(af[mt], bfr[nt], acc[mt][nt]);
        }
        __syncthreads();
    }
#pragma unroll
    for (int mt = 0; mt < 4; ++mt) {
#pragma unroll
        for (int nt = 0; nt < 4; ++nt) {
            int col = n0 + wn * 64 + nt * 16 + lc;
#pragma unroll
            for (int r = 0; r < 4; ++r) {
                int row = m0 + wm * 64 + mt * 16 + quad * 4 + r;
                if constexpr (MODE == 1) {
                    ((float*)C0)[(size_t)row * N + col] = acc[mt][nt][r];
                } else if constexpr (MODE == 0) {
                    (((ushort_t*)C0) + (long)blockIdx.z * sC)[(size_t)row * N + col] = f2bf(acc[mt][nt][r]);
                } else {
                    // row = feature f, col = token (b*2048+j): write VT[(b*1024+f)*2048 + j]
                    ((ushort_t*)C0)[(size_t)(col >> 11) * 2097152 + (size_t)row * 2048 + (col & 2047)] =
                        f2bf(acc[mt][nt][r]);
                }
            }
        }
    }
}

// ---------------- flash attention, S^T = K*Q^T, K dbuf via reg+ds_write, lgkm-only barrier ----------------
// NT bias stores are never vmcnt-drained: K handoff is lgkmcnt-tracked (ds_write), so the
// in-loop barrier needs only s_waitcnt lgkmcnt(0) + raw s_barrier. [R10->R11 change]
// 1-D grid 512: bh = id&31 (XCD-local K/V reuse), qt = id>>5. 4 waves, wave w owns q [w*32, w*32+32)
__global__ __launch_bounds__(256, 2) void attn_k(const ushort_t* __restrict__ Qg,
                                                 const ushort_t* __restrict__ Kg,
                                                 const ushort_t* __restrict__ VTg,
                                                 ushort_t* __restrict__ Ctx,
                                                 const unsigned char* __restrict__ lut,
                                                 const float* __restrict__ table,
                                                 float* __restrict__ bias_out) {
    __shared__ ushort_t Kbuf[2][128 * 64];   // K tiles [j][d] swizzled, double-buffered
    __shared__ ushort_t Pws[4 * 32 * 40];    // per-wave packed P [q][j-chunk]
    __shared__ float diag[2][256];           // raw bias diagonal, double-buffered

    const int tid = threadIdx.x, l = tid & 63, w = tid >> 6;
    const int quad = l >> 4, lc = l & 15;
    const int id = blockIdx.x;
    const int bh = id & 31, b = bh >> 4, h = bh & 15;
    const int q0 = (id >> 5) * 128;
    const size_t tokbase = (size_t)b * 2048;

    const int rK = l >> 3;
    const int cK = ((l & 7) ^ rK) * 8;
    const int ldsc = (l & 7) * 8;            // LDS chunk this lane stages

    // ---- prologue: Q -> Kbuf[1], K(kt0) -> Kbuf[0], diag[0] (glds16 + full sync, once) ----
#pragma unroll
    for (int t = 0; t < 4; ++t) {
        int row0 = w * 32 + t * 8;
        glds16(Qg + (tokbase + q0 + row0 + rK) * 1024 + h * 64 + cK, &Kbuf[1][row0 * 64]);
        glds16(Kg + (tokbase + row0 + rK) * 1024 + h * 64 + cK, &Kbuf[0][row0 * 64]);
    }
    if (tid < 255) diag[0][tid] = table[(int)lut[tid + 1920 - q0] * 16 + h];
    __syncthreads();

    // Q fragments (B-operand): lane holds Q[w*32+nt*16+lc][ko*32+quad*8+i]
    bf16x8 qf[2][2];
#pragma unroll
    for (int nt = 0; nt < 2; ++nt)
#pragma unroll
        for (int ko = 0; ko < 2; ++ko) {
            int row = w * 32 + nt * 16 + lc;
            int ch = ((ko * 4 + quad) ^ (lc & 7)) * 8;
            qf[nt][ko] = *(const bf16x8*)&Kbuf[1][row * 64 + ch];
        }
    __syncthreads();   // Kbuf[1] free for kt=0's prefetch of K(kt=1)

    float mstate[2] = {-1e30f, -1e30f};
    float lstate[2] = {0.f, 0.f};
    f32x4 acco[4][2] = {};
    ushort_t* Pw = &Pws[w * 1280];         // 32 q-rows x 40 u16
    const int cb0 = quad * 4 - (w * 32 + lc) + 127;
    const int cxor = lc & 3;               // P chunk swizzle
    const ushort_t* VTbase = VTg + (size_t)(b * 1024 + h * 64) * 2048;

    const int bjf = (tid & 15) * 4 + b * 64;   // bias patch j offset within 128-tile
    const int big = tid >> 4;

    for (int kt = 0; kt < 16; ++kt) {
        const int j0 = kt * 128;
        const int cur = kt & 1, nxt = cur ^ 1;
        const ushort_t* Kc = Kbuf[cur];
        const float* dc = diag[cur];

        // ---- K-next + diag-next into REGISTERS (latency starts now; ds_write after QK) ----
        us8 knx[4];
        float dnext = 0.f;
        if (kt < 15) {
            const int jn = j0 + 128;
#pragma unroll
            for (int t = 0; t < 4; ++t) {
                int row = w * 32 + t * 8 + rK;
                knx[t] = *(const us8*)(Kg + (tokbase + jn + row) * 1024 + h * 64 + cK);
            }
            if (tid < 255) dnext = table[(int)lut[jn - q0 + tid + 1920] * 16 + h];
        }

        // ---- V fragments direct from global (A-operand rows d, k-index j) ----
        bf16x8 vf[4][4];
#pragma unroll
        for (int kk = 0; kk < 4; ++kk)
#pragma unroll
            for (int dt = 0; dt < 4; ++dt)
                vf[kk][dt] = *(const bf16x8*)(VTbase + (size_t)(dt * 16 + lc) * 2048 +
                                              j0 + kk * 32 + quad * 8);

        // ---- fused position_bias patch NT stores (drain in background; never waited) ----
        {
            float* outp = bias_out + ((size_t)h * 2048 + q0) * 2048 + j0;
#pragma unroll
            for (int rr = 0; rr < 8; ++rr) {
                int il = big + 16 * rr;
                int d0 = bjf - il + 127;
                f32x4 v;
                v[0] = dc[d0]; v[1] = dc[d0 + 1]; v[2] = dc[d0 + 2]; v[3] = dc[d0 + 3];
                __builtin_nontemporal_store(v, (f32x4*)(outp + (size_t)il * 2048 + bjf));
            }
        }

        // ---- S^T = K Q^T : D[j][q], A = K rows (LDS), B = Q rows (Q pre-scaled by log2e) ----
        f32x4 accs[8][2] = {};
#pragma unroll
        for (int ko = 0; ko < 2; ++ko) {
            const int ch = ((ko * 4 + quad) ^ (lc & 7)) * 8;
#pragma unroll
            for (int mt = 0; mt < 8; ++mt) {
                bf16x8 kf = *(const bf16x8*)&Kc[(mt * 16 + lc) * 64 + ch];
                accs[mt][0] = MFMA16(kf, qf[0][ko], accs[mt][0]);
                accs[mt][1] = MFMA16(kf, qf[1][ko], accs[mt][1]);
            }
        }

        // ---- commit K-next to LDS (reg dep forces exact vmcnt wait for knx only) ----
        if (kt < 15) {
#pragma unroll
            for (int t = 0; t < 4; ++t) {
                int row = w * 32 + t * 8 + rK;
                *(us8*)&Kbuf[nxt][row * 64 + ldsc] = knx[t];
            }
            if (tid < 255) diag[nxt][tid] = dnext;
        }

        // ---- + bias via fma(raw, log2e) with rolling reuse (d = mt for nt=0, mt-1 for nt=1) ----
        float dprev[4], dcur[4];
#pragma unroll
        for (int r = 0; r < 4; ++r) dprev[r] = dc[cb0 - 16 + r];
#pragma unroll
        for (int mt = 0; mt < 8; ++mt) {
#pragma unroll
            for (int r = 0; r < 4; ++r) dcur[r] = dc[cb0 + mt * 16 + r];
#pragma unroll
            for (int r = 0; r < 4; ++r) {
                accs[mt][0][r] = fmaf(dcur[r], LOG2E, accs[mt][0][r]);
                accs[mt][1][r] = fmaf(dprev[r], LOG2E, accs[mt][1][r]);
            }
#pragma unroll
            for (int r = 0; r < 4; ++r) dprev[r] = dcur[r];
        }

        // ---- online softmax in exp2 domain: q-row = nt*16+lc over 4 quad-lanes ----
#pragma unroll
        for (int nt = 0; nt < 2; ++nt) {
            float mx = accs[0][nt][0];
#pragma unroll
            for (int mt = 0; mt < 8; ++mt)
#pragma unroll
                for (int r = 0; r < 4; ++r) mx = fmaxf(mx, accs[mt][nt][r]);
            mx = fmaxf(mx, __shfl_xor(mx, 16, 64));
            mx = fmaxf(mx, __shfl_xor(mx, 32, 64));
            float mo = mstate[nt], mn = fmaxf(mo, mx);
            float alpha = __builtin_amdgcn_exp2f(mo - mn);
            mstate[nt] = mn;
            float rs = 0.f;
#pragma unroll
            for (int mt = 0; mt < 8; ++mt)
#pragma unroll
                for (int r = 0; r < 4; ++r) {
                    float p = __builtin_amdgcn_exp2f(accs[mt][nt][r] - mn);
                    accs[mt][nt][r] = p;
                    rs += p;
                }
            rs += __shfl_xor(rs, 16, 64);
            rs += __shfl_xor(rs, 32, 64);
            lstate[nt] = lstate[nt] * alpha + rs;
#pragma unroll
            for (int dt = 0; dt < 4; ++dt) acco[dt][nt] *= alpha;
        }

        // ---- O^T += V^T P^T; P wave-private LDS roundtrip (b64 writes, b128 reads) ----
#pragma unroll
        for (int kk = 0; kk < 4; ++kk) {
#pragma unroll
            for (int half = 0; half < 2; ++half) {
                int mt = kk * 2 + half;
                int c = half * 2 + (quad >> 1);
                int coff = ((c ^ cxor) * 8 + (quad & 1) * 4);
#pragma unroll
                for (int nt = 0; nt < 2; ++nt) {
                    us4 o;
#pragma unroll
                    for (int r = 0; r < 4; ++r) o[r] = f2bf(accs[mt][nt][r]);
                    *(us4*)&Pw[(nt * 16 + lc) * 40 + coff] = o;
                }
            }
            bf16x8 pf[2];
#pragma unroll
            for (int nt = 0; nt < 2; ++nt)
                pf[nt] = *(const bf16x8*)&Pw[(nt * 16 + lc) * 40 + (quad ^ cxor) * 8];
#pragma unroll
            for (int dt = 0; dt < 4; ++dt)
#pragma unroll
                for (int nt = 0; nt < 2; ++nt)
                    acco[dt][nt] = MFMA16(vf[kk][dt], pf[nt], acco[dt][nt]);
        }

        // ---- lgkm-only barrier: ds_writes visible, NT stores left in flight ----
        if (kt < 15) {
            __builtin_amdgcn_s_waitcnt(0xC07F);   // lgkmcnt(0); vmcnt=63, expcnt=7 (unconstrained)
            __builtin_amdgcn_s_barrier();
        }
    }

    // ---- epilogue: O^T lane holds (d = dt*16+quad*4+r, q = w*32+nt*16+lc) ----
#pragma unroll
    for (int nt = 0; nt < 2; ++nt) {
        float inv = 1.0f / lstate[nt];
        size_t row = tokbase + q0 + w * 32 + nt * 16 + lc;
#pragma unroll
        for (int dt = 0; dt < 4; ++dt) {
            us4 o;
#pragma unroll
            for (int r = 0; r < 4; ++r) o[r] = f2bf(acco[dt][nt][r] * inv);
            *(us4*)&Ctx[row * 1024 + h * 64 + dt * 16 + quad * 4] = o;
        }
    }
}

extern "C" void kernel_launch(void* const* d_in, const int* in_sizes, int n_in,
                              void* d_out, int out_size, void* d_ws, size_t ws_size,
                              hipStream_t stream) {
    const float* hidden = (const float*)d_in[0];
    const float* Wq = (const float*)d_in[1];
    const float* Wk = (const float*)d_in[2];
    const float* Wv = (const float*)d_in[3];
    const float* Wo = (const float*)d_in[4];
    const float* table = (const float*)d_in[5];

    char* ws = (char*)d_ws;
    ushort_t* Xb  = (ushort_t*)(ws);                    // [4096][1024] bf16
    ushort_t* Wb  = (ushort_t*)(ws + 8388608);          // Wq(*log2e),Wk,Wv,Wo each [1024][1024]
    ushort_t* Qg  = (ushort_t*)(ws + 16777216);         // [4096][1024]
    ushort_t* Kgp = (ushort_t*)(ws + 25165824);         // [4096][1024]
    ushort_t* VTg = (ushort_t*)(ws + 33554432);         // [(b*1024+f)][2048]
    ushort_t* Ctx = (ushort_t*)(ws + 41943040);         // [4096][1024]
    unsigned char* lutp = (unsigned char*)(ws + 50331648);

    float* out0 = (float*)d_out;
    float* out1 = out0 + 4194304;

    cast_all_k<<<8193, 256, 0, stream>>>(hidden, Wq, Wk, Wv, Wo, Xb, Wb, lutp);

    // Q, K projections: C[token][feat] bf16
    gemm_bt_k<0><<<dim3(8, 32, 2), 256, 0, stream>>>(Xb, Wb, (void*)Qg,
                                                     4096, 1024, 1024, 1048576, 4194304);
    // V^T: C[f][token] -> VT[(b*1024+f)][j]
    gemm_bt_k<2><<<dim3(32, 8, 1), 256, 0, stream>>>(Wb + 2097152, Xb, (void*)VTg,
                                                     1024, 4096, 1024, 0, 0);
    attn_k<<<dim3(512), 256, 0, stream>>>(Qg, Kgp, VTg, Ctx, lutp, table, out1);
    gemm_bt_k<1><<<dim3(8, 32, 1), 256, 0, stream>>>(Ctx, Wb + 3145728, (void*)out0,
                                                     4096, 1024, 1024, 0, 0);
}